// Round 8
// baseline (93.227 us; speedup 1.0000x reference)
//
#include <hip/hip_runtime.h>
#include <hip/hip_bf16.h>

typedef __bf16 bf16x8 __attribute__((ext_vector_type(8)));
typedef float f32x4 __attribute__((ext_vector_type(4)));

#define B_    8
#define NTOK  4096
#define CIN   512
#define COUT  512
#define SDIM  512
#define EPSF  1e-8f

// ---------------------------------------------------------------------------
// K1: m[b][i] = style[b,:] . mod_w[i,:] + mod_b[i] + 1    (one wave per output)
// ---------------------------------------------------------------------------
__global__ __launch_bounds__(256) void k_stylefc(
    const float* __restrict__ style, const float* __restrict__ mod_w,
    const float* __restrict__ mod_b, float* __restrict__ m_out) {
  int gw   = (blockIdx.x * 256 + threadIdx.x) >> 6;  // 0..4095
  int lane = threadIdx.x & 63;
  int b = gw >> 9;
  int i = gw & 511;
  const float* srow = style + (size_t)b * SDIM;
  const float* wrow = mod_w + (size_t)i * SDIM;
  float acc = 0.f;
#pragma unroll
  for (int k = 0; k < SDIM; k += 64) acc += srow[k + lane] * wrow[k + lane];
#pragma unroll
  for (int off = 32; off; off >>= 1) acc += __shfl_xor(acc, off, 64);
  if (lane == 0) m_out[b * CIN + i] = acc + mod_b[i] + 1.0f;
}

// ---------------------------------------------------------------------------
// K2 (fused): per output-channel o (one block each):
//  - demod[b][o] = rsqrt( sum_k (weight[k][o]*m[b][k])^2 + eps ),  8 b
//  - wimg: pre-swizzled bf16 W image (R7-verified numerics/layout):
//    [nb(4)][kt(16)][row(128)][64B]:
//      byte = nb*131072 + kt*8192 + row*64 + slot*16 + (k&7)*2
//      slot = ((k&31)>>3) ^ ((row>>1)&3),  row = o&127, nb = o>>7
// ---------------------------------------------------------------------------
__global__ __launch_bounds__(256) void k_wprep(
    const float* __restrict__ weight, const float* __restrict__ m_buf,
    __bf16* __restrict__ wimg, float* __restrict__ demod) {
  int o = blockIdx.x;
  int tid = threadIdx.x;
  int wid = tid >> 6, lane = tid & 63;
  int nb = o >> 7, row = o & 127;
  float acc[B_] = {0.f, 0.f, 0.f, 0.f, 0.f, 0.f, 0.f, 0.f};
#pragma unroll
  for (int rep = 0; rep < 2; ++rep) {
    int k = tid + rep * 256;
    float w = weight[(size_t)k * COUT + o];
    int kt = k >> 5, kl = k & 31, s = kl >> 3, ko = kl & 7;
    int sl = s ^ ((row >> 1) & 3);
    *(__bf16*)((char*)wimg + (size_t)nb * 131072 + kt * 8192 + row * 64 +
               sl * 16 + ko * 2) = (__bf16)w;
#pragma unroll
    for (int b = 0; b < B_; ++b) {
      float wm = w * m_buf[b * CIN + k];
      acc[b] += wm * wm;
    }
  }
  __shared__ float red[4][B_];
#pragma unroll
  for (int b = 0; b < B_; ++b) {
    float v = acc[b];
#pragma unroll
    for (int off = 32; off; off >>= 1) v += __shfl_xor(v, off, 64);
    if (lane == 0) red[wid][b] = v;
  }
  __syncthreads();
  if (tid < B_) {
    float s = red[0][tid] + red[1][tid] + red[2][tid] + red[3][tid];
    demod[tid * COUT + o] = rsqrtf(s + EPSF);
  }
}

// ---------------------------------------------------------------------------
// async global->LDS: dest = wave-uniform LDS base (+lane*16 by HW), src per-lane
// ---------------------------------------------------------------------------
__device__ __forceinline__ void async_copy16(void* lds_dst, const void* gsrc) {
  __builtin_amdgcn_global_load_lds(
      (const __attribute__((address_space(1))) unsigned int*)gsrc,
      (__attribute__((address_space(3))) unsigned int*)lds_dst, 16, 0, 0);
}

// ---------------------------------------------------------------------------
// K3: out[b,t,o] = demod[b][o] * sum_k (x[b,t,k]*m[b][k]) * W[k][o]
// Tile 128 o x 128 tok, 256 thr / 4 waves (wave-tile 64x64), BK=32, 16 kt.
// NO per-phase vmcnt(0)-drain:  per kt:
//   cvt x(kt)            <- reg dep drains own x(kt) AND older W(kt) gloads
//   raw s_barrier        <- joins waves AFTER each drained its W(kt) portion
//   issue W(kt+1), x(kt+1)  <- full phase of flight, never force-drained
//   ds_read W(kt) + 16 MFMA
// W: dbuf 2x8KB LDS via global_load_lds from pre-swizzled image (R5/R7
//    verified 0-conflict pattern).  X: global->reg direct, *m, bf16 cvt.
// 4 nb-blocks of one x-panel pinned to one XCD (x HBM-read once).
// ---------------------------------------------------------------------------
__global__ __launch_bounds__(256) void k_gemm(
    const float* __restrict__ x, const __bf16* __restrict__ wimg,
    const float* __restrict__ m_buf, const float* __restrict__ demod,
    float* __restrict__ out) {
  // 1024 blocks = 8 xcd * 32 panels * 4 nb
  int bid = blockIdx.x;
  int xcd = bid & 7;
  int j   = bid >> 3;                  // 0..127
  int panel = xcd * 32 + (j >> 2);     // 0..255
  int nb  = j & 3;
  int b   = panel >> 5, tb = panel & 31;

  __shared__ char Wl[2][8192];         // W dbuf, 16 KB total

  int tid = threadIdx.x;
  int wid = tid >> 6, lane = tid & 63;
  int ln15 = lane & 15, s = lane >> 4;
  int ow = wid & 1, tw = wid >> 1;

  f32x4 acc[4][4] = {};  // [mm: o-frag][nn: tok-frag]

  const float* xb = x + (size_t)(b * NTOK + tb * 128) * CIN;
  const float* xpb0 = xb + (size_t)(tw * 64 +  0 + ln15) * CIN + s * 8;
  const float* xpb1 = xb + (size_t)(tw * 64 + 16 + ln15) * CIN + s * 8;
  const float* xpb2 = xb + (size_t)(tw * 64 + 32 + ln15) * CIN + s * 8;
  const float* xpb3 = xb + (size_t)(tw * 64 + 48 + ln15) * CIN + s * 8;
  const float* mpb  = m_buf + b * CIN + s * 8;
  const char*  wsrc = (const char*)wimg + (size_t)nb * 131072;

  float4 xp[4][2], mp[2];
  auto issueW = [&](int kt) {
    const char* src = wsrc + (size_t)kt * 8192;
    char* dst = Wl[kt & 1];
#pragma unroll
    for (int q = 0; q < 2; ++q) {
      int off = (q * 4 + wid) * 1024;
      async_copy16(dst + off, src + off + lane * 16);
    }
  };
  auto issueX = [&](int kt) {
    const float* p0 = xpb0 + kt * 32;
    const float* p1 = xpb1 + kt * 32;
    const float* p2 = xpb2 + kt * 32;
    const float* p3 = xpb3 + kt * 32;
    xp[0][0] = *(const float4*)p0;  xp[0][1] = *(const float4*)(p0 + 4);
    xp[1][0] = *(const float4*)p1;  xp[1][1] = *(const float4*)(p1 + 4);
    xp[2][0] = *(const float4*)p2;  xp[2][1] = *(const float4*)(p2 + 4);
    xp[3][0] = *(const float4*)p3;  xp[3][1] = *(const float4*)(p3 + 4);
    mp[0] = *(const float4*)(mpb + kt * 32);
    mp[1] = *(const float4*)(mpb + kt * 32 + 4);
  };

  // prologue: issue phase-0 loads
  issueW(0);
  issueX(0);

#pragma unroll
  for (int kt = 0; kt < 16; ++kt) {
    // convert x(kt): reg deps drain own x/m(kt) and the OLDER W(kt) gloads
    bf16x8 xf[4];
#pragma unroll
    for (int nn = 0; nn < 4; ++nn) {
      bf16x8 h;
      h[0] = (__bf16)(xp[nn][0].x * mp[0].x);
      h[1] = (__bf16)(xp[nn][0].y * mp[0].y);
      h[2] = (__bf16)(xp[nn][0].z * mp[0].z);
      h[3] = (__bf16)(xp[nn][0].w * mp[0].w);
      h[4] = (__bf16)(xp[nn][1].x * mp[1].x);
      h[5] = (__bf16)(xp[nn][1].y * mp[1].y);
      h[6] = (__bf16)(xp[nn][1].z * mp[1].z);
      h[7] = (__bf16)(xp[nn][1].w * mp[1].w);
      xf[nn] = h;
    }
    // raw barrier: all waves have drained their own W(kt) portion -> resident
    __builtin_amdgcn_sched_barrier(0);
    __builtin_amdgcn_s_barrier();
    __builtin_amdgcn_sched_barrier(0);
    // issue next phase (full phase of flight; never force-drained here)
    if (kt < 15) {
      issueW(kt + 1);   // other buffer; its previous readers are past barrier
      issueX(kt + 1);
    }
    // ds_read W(kt) fragments (0-conflict swizzle) + MFMA
    const char* Wb = Wl[kt & 1];
    bf16x8 wf[4];
#pragma unroll
    for (int mm = 0; mm < 4; ++mm) {
      int r = ow * 64 + mm * 16 + ln15;
      wf[mm] = *(const bf16x8*)(Wb + r * 64 + ((s ^ ((r >> 1) & 3)) << 4));
    }
#pragma unroll
    for (int mm = 0; mm < 4; ++mm)
#pragma unroll
      for (int nn = 0; nn < 4; ++nn)
        acc[mm][nn] = __builtin_amdgcn_mfma_f32_16x16x32_bf16(
            wf[mm], xf[nn], acc[mm][nn], 0, 0, 0);
  }

  // ---- epilogue: out[t][o..o+3] = acc * demod, float4 stores ----
  float* ob = out + (size_t)(b * NTOK + tb * 128) * COUT + nb * 128 + ow * 64;
  const float* dr = demod + b * COUT + nb * 128 + ow * 64;
#pragma unroll
  for (int mm = 0; mm < 4; ++mm) {
    int o = mm * 16 + s * 4;
    float4 dv = *(const float4*)(dr + o);
#pragma unroll
    for (int nn = 0; nn < 4; ++nn) {
      int t = tw * 64 + nn * 16 + ln15;
      f32x4 r;
      r[0] = acc[mm][nn][0] * dv.x;
      r[1] = acc[mm][nn][1] * dv.y;
      r[2] = acc[mm][nn][2] * dv.z;
      r[3] = acc[mm][nn][3] * dv.w;
      *(f32x4*)(ob + (size_t)t * COUT + o) = r;
    }
  }
}

// ---------------------------------------------------------------------------
extern "C" void kernel_launch(void* const* d_in, const int* in_sizes, int n_in,
                              void* d_out, int out_size, void* d_ws, size_t ws_size,
                              hipStream_t stream) {
  const float* x      = (const float*)d_in[0];  // (8,4096,512)
  const float* style  = (const float*)d_in[1];  // (8,512)
  const float* weight = (const float*)d_in[2];  // (1,512,512)
  const float* mod_w  = (const float*)d_in[3];  // (512,512)
  const float* mod_b  = (const float*)d_in[4];  // (512,)
  float* out = (float*)d_out;

  // ws: m[8*512] f32 (16KB) | demod[8*512] f32 (16KB) | wimg 512KB
  float*  m_buf = (float*)d_ws;
  float*  demod = m_buf + B_ * CIN;
  __bf16* wimg  = (__bf16*)((char*)d_ws + 2 * B_ * CIN * sizeof(float));

  k_stylefc<<<dim3((B_ * CIN) / 4), dim3(256), 0, stream>>>(style, mod_w, mod_b, m_buf);
  k_wprep<<<dim3(COUT), dim3(256), 0, stream>>>(weight, m_buf, wimg, demod);
  k_gemm<<<dim3(1024), dim3(256), 0, stream>>>(x, wimg, m_buf, demod, out);
}

// Round 9
// 50.059 us; speedup vs baseline: 1.8623x; 1.8623x over previous
//
#include <hip/hip_runtime.h>
#include <hip/hip_bf16.h>

typedef __bf16 bf16x8 __attribute__((ext_vector_type(8)));
typedef float f32x4 __attribute__((ext_vector_type(4)));

#define B_    8
#define NTOK  4096
#define CIN   512
#define COUT  512
#define SDIM  512
#define EPSF  1e-8f

// ---------------------------------------------------------------------------
// K1: m[b][i] = style[b,:] . mod_w[i,:] + mod_b[i] + 1    (one wave per output)
// ---------------------------------------------------------------------------
__global__ __launch_bounds__(256) void k_stylefc(
    const float* __restrict__ style, const float* __restrict__ mod_w,
    const float* __restrict__ mod_b, float* __restrict__ m_out) {
  int gw   = (blockIdx.x * 256 + threadIdx.x) >> 6;  // 0..4095
  int lane = threadIdx.x & 63;
  int b = gw >> 9;
  int i = gw & 511;
  const float* srow = style + (size_t)b * SDIM;
  const float* wrow = mod_w + (size_t)i * SDIM;
  float acc = 0.f;
#pragma unroll
  for (int k = 0; k < SDIM; k += 64) acc += srow[k + lane] * wrow[k + lane];
#pragma unroll
  for (int off = 32; off; off >>= 1) acc += __shfl_xor(acc, off, 64);
  if (lane == 0) m_out[b * CIN + i] = acc + mod_b[i] + 1.0f;
}

// ---------------------------------------------------------------------------
// K2: fold EVERYTHING into the weight:
//   demod[b][o] = rsqrt( sum_k (W[k][o]*m[b][k])^2 + eps )   (f32, internal)
//   Wfinal[b][k][o] = W[k][o] * m[b][k] * demod[b][o]  -> bf16, written as a
//   pre-swizzled image the GEMM can global_load_lds LINEARLY:
//   slab(b,nb,kt) = ((b*2+nb)*8 + kt) * 32768 bytes, tile [row(256)][128B]:
//     byte = row*128 + ((k'>>3 ^ (row&7))<<4) + (k&7)*2,  k'=k&63, row=o&255
// one block (256 thr) per o
// ---------------------------------------------------------------------------
__global__ __launch_bounds__(256) void k_wfin(
    const float* __restrict__ weight, const float* __restrict__ m_buf,
    __bf16* __restrict__ wimg) {
  int o = blockIdx.x;
  int tid = threadIdx.x;
  int wid = tid >> 6, lane = tid & 63;
  int nb = o >> 8, row = o & 255;
  float wv[2];
  float acc[B_] = {0.f, 0.f, 0.f, 0.f, 0.f, 0.f, 0.f, 0.f};
#pragma unroll
  for (int rep = 0; rep < 2; ++rep) {
    int k = tid + rep * 256;
    float w = weight[(size_t)k * COUT + o];
    wv[rep] = w;
#pragma unroll
    for (int b = 0; b < B_; ++b) {
      float t = w * m_buf[b * CIN + k];
      acc[b] += t * t;
    }
  }
  __shared__ float red[4][B_];
  __shared__ float dsm[B_];
#pragma unroll
  for (int b = 0; b < B_; ++b) {
    float v = acc[b];
#pragma unroll
    for (int off = 32; off; off >>= 1) v += __shfl_xor(v, off, 64);
    if (lane == 0) red[wid][b] = v;
  }
  __syncthreads();
  if (tid < B_)
    dsm[tid] = rsqrtf(red[0][tid] + red[1][tid] + red[2][tid] + red[3][tid] + EPSF);
  __syncthreads();
#pragma unroll
  for (int rep = 0; rep < 2; ++rep) {
    int k = tid + rep * 256;
    int kt = k >> 6;
    int sl = ((k >> 3) & 7) ^ (row & 7);
    char* base = (char*)wimg + (size_t)row * 128 + sl * 16 + (k & 7) * 2;
#pragma unroll
    for (int b = 0; b < B_; ++b) {
      float val = wv[rep] * m_buf[b * CIN + k] * dsm[b];
      *(__bf16*)(base + (size_t)((b * 2 + nb) * 8 + kt) * 32768) = (__bf16)val;
    }
  }
}

// ---------------------------------------------------------------------------
// async global->LDS: dest = wave-uniform LDS base (+lane*16 by HW), src per-lane
// ---------------------------------------------------------------------------
__device__ __forceinline__ void async_copy16(void* lds_dst, const void* gsrc) {
  __builtin_amdgcn_global_load_lds(
      (const __attribute__((address_space(1))) unsigned int*)gsrc,
      (__attribute__((address_space(3))) unsigned int*)lds_dst, 16, 0, 0);
}

// ---------------------------------------------------------------------------
// K3: pure bf16 GEMM  out[256tok x 256o] += bf16(x) @ Wfinal[b]
// 256 blocks (1/CU) x 512 thr (8 waves: 2 tok-halves x 4 o-groups).
// BK=64, 8 K-tiles, dbuf 128 KB LDS (X 2x32K | W 2x32K), XOR slot^(row&7).
// Per kt: issue x(kt+1)->regs + W(kt+1)->LDS-DMA at TOP; 64 MFMA; cvt+ds_write
// x(kt+1); single raw barrier with own-drain (loads get a full tile of
// flight; no early vmcnt(0)).  Epilogue: plain float4 stores (demod folded).
// ---------------------------------------------------------------------------
__global__ __launch_bounds__(512) void k_gemm(
    const float* __restrict__ x, const __bf16* __restrict__ wimg,
    float* __restrict__ out) {
  // 256 blocks = 8 xcd * 16 m-panels * 2 nb (nb-pair of a panel same XCD)
  int bid = blockIdx.x;
  int xcd = bid & 7;
  int i   = bid >> 3;                 // 0..31
  int panel = xcd * 16 + (i >> 1);    // 0..127
  int nb  = i & 1;
  int b   = panel >> 4, tb = panel & 15;

  extern __shared__ char lds[];       // 128 KB
  char* Xl0 = lds;
  char* Xl1 = lds + 32768;
  char* Wl0 = lds + 65536;
  char* Wl1 = lds + 98304;

  int tid = threadIdx.x;
  int wid = tid >> 6, lane = tid & 63;
  int ln15 = lane & 15, s = lane >> 4;
  int ow = wid & 3;                   // o-group (A-operand): 4 x 64 rows
  int tw = wid >> 2;                  // token-half (B-operand): 2 x 128 rows

  const float* xb    = x + (size_t)(b * NTOK + tb * 256) * CIN;
  const char*  wslab = (const char*)wimg + (size_t)((b * 2 + nb) * 8) * 32768;

  // x staging: thread -> row=tid>>1 (256 rows), kh32=tid&1 (32 floats)
  int srow = tid >> 1, skh = tid & 1;
  const float* xsrc = xb + (size_t)srow * CIN + skh * 32;
  int swbase = srow * 128;

  f32x4 xs[8];
  auto issueX = [&](int kt) {
    const float* p = xsrc + kt * 64;
#pragma unroll
    for (int j = 0; j < 8; ++j) xs[j] = *(const f32x4*)(p + j * 4);
  };
  auto issueB = [&](int kt, char* dst) {
    const char* src = wslab + (size_t)kt * 32768;
#pragma unroll
    for (int q = 0; q < 4; ++q) {
      int off = (q * 8 + wid) * 1024;
      async_copy16(dst + off, src + off + lane * 16);
    }
  };
  auto writeX = [&](char* Xb) {
    char* dst = Xb + swbase;
#pragma unroll
    for (int j = 0; j < 4; ++j) {
      bf16x8 h;
      h[0] = (__bf16)xs[j * 2][0];     h[1] = (__bf16)xs[j * 2][1];
      h[2] = (__bf16)xs[j * 2][2];     h[3] = (__bf16)xs[j * 2][3];
      h[4] = (__bf16)xs[j * 2 + 1][0]; h[5] = (__bf16)xs[j * 2 + 1][1];
      h[6] = (__bf16)xs[j * 2 + 1][2]; h[7] = (__bf16)xs[j * 2 + 1][3];
      *(bf16x8*)(dst + (((skh * 4 + j) ^ (srow & 7)) << 4)) = h;
    }
  };

  f32x4 acc[4][8] = {};  // [mm: o-frag][nn: tok-frag]

  auto compute = [&](const char* Xb, const char* Wb) {
    bf16x8 wf[4][2];
#pragma unroll
    for (int mm = 0; mm < 4; ++mm) {
      int r = ow * 64 + mm * 16 + ln15;
#pragma unroll
      for (int kh = 0; kh < 2; ++kh)
        wf[mm][kh] = *(const bf16x8*)(Wb + r * 128 +
                                      (((kh * 4 + s) ^ (r & 7)) << 4));
    }
    __builtin_amdgcn_s_setprio(1);
#pragma unroll
    for (int nn = 0; nn < 8; ++nn) {
      int rt = tw * 128 + nn * 16 + ln15;
      bf16x8 xf0 = *(const bf16x8*)(Xb + rt * 128 + ((s ^ (rt & 7)) << 4));
      bf16x8 xf1 = *(const bf16x8*)(Xb + rt * 128 + (((4 + s) ^ (rt & 7)) << 4));
#pragma unroll
      for (int mm = 0; mm < 4; ++mm) {
        acc[mm][nn] = __builtin_amdgcn_mfma_f32_16x16x32_bf16(
            wf[mm][0], xf0, acc[mm][nn], 0, 0, 0);
        acc[mm][nn] = __builtin_amdgcn_mfma_f32_16x16x32_bf16(
            wf[mm][1], xf1, acc[mm][nn], 0, 0, 0);
      }
    }
    __builtin_amdgcn_s_setprio(0);
  };

  // ---- prologue: stage kt=0 ----
  issueX(0);
  issueB(0, Wl0);
  writeX(Xl0);                                  // auto vmcnt waits x only
  asm volatile("s_waitcnt vmcnt(0)" ::: "memory");
  asm volatile("s_waitcnt lgkmcnt(0)" ::: "memory");
  __builtin_amdgcn_sched_barrier(0);
  __builtin_amdgcn_s_barrier();
  __builtin_amdgcn_sched_barrier(0);

  // ---- K loop: 1 barrier per kt; all loads issued a full tile early ----
#pragma unroll
  for (int kt = 0; kt < 8; ++kt) {
    char* Xc = (kt & 1) ? Xl1 : Xl0;
    char* Wc = (kt & 1) ? Wl1 : Wl0;
    char* Xn = (kt & 1) ? Xl0 : Xl1;
    char* Wn = (kt & 1) ? Wl0 : Wl1;
    if (kt < 7) {
      issueX(kt + 1);      // x first (oldest) -> cvt's auto-wait leaves W DMA
      issueB(kt + 1, Wn);  // in flight through the whole compute phase
    }
    compute(Xc, Wc);
    if (kt < 7) {
      writeX(Xn);          // auto vmcnt(4) waits x; 4 W-DMAs keep flying
      asm volatile("s_waitcnt vmcnt(0)" ::: "memory");   // W: ~full-tile flight
      asm volatile("s_waitcnt lgkmcnt(0)" ::: "memory"); // my ds_writes visible
      __builtin_amdgcn_sched_barrier(0);
      __builtin_amdgcn_s_barrier();
      __builtin_amdgcn_sched_barrier(0);
    }
  }

  // ---- epilogue: plain float4 stores (demod already folded into W) ----
  float* ob = out + (size_t)(b * NTOK + tb * 256) * COUT + nb * 256;
#pragma unroll
  for (int nn = 0; nn < 8; ++nn) {
    int token = tw * 128 + nn * 16 + ln15;
    float* orow = ob + (size_t)token * COUT;
#pragma unroll
    for (int mm = 0; mm < 4; ++mm) {
      int o = ow * 64 + mm * 16 + s * 4;
      *(f32x4*)(orow + o) = acc[mm][nn];
    }
  }
}

// ---------------------------------------------------------------------------
extern "C" void kernel_launch(void* const* d_in, const int* in_sizes, int n_in,
                              void* d_out, int out_size, void* d_ws, size_t ws_size,
                              hipStream_t stream) {
  const float* x      = (const float*)d_in[0];  // (8,4096,512)
  const float* style  = (const float*)d_in[1];  // (8,512)
  const float* weight = (const float*)d_in[2];  // (1,512,512)
  const float* mod_w  = (const float*)d_in[3];  // (512,512)
  const float* mod_b  = (const float*)d_in[4];  // (512,)
  float* out = (float*)d_out;

  // ws: m[8*512] f32 (16KB) | pad | wimg 4 MB (pre-swizzled Wfinal image)
  float*  m_buf = (float*)d_ws;
  __bf16* wimg  = (__bf16*)((char*)d_ws + 32768);

  hipFuncSetAttribute((const void*)k_gemm,
                      hipFuncAttributeMaxDynamicSharedMemorySize, 131072);

  k_stylefc<<<dim3((B_ * CIN) / 4), dim3(256), 0, stream>>>(style, mod_w, mod_b, m_buf);
  k_wfin<<<dim3(COUT), dim3(256), 0, stream>>>(weight, m_buf, wimg);
  k_gemm<<<dim3(256), dim3(512), 131072, stream>>>(x, wimg, out);
}